// Round 5
// baseline (4934.830 us; speedup 1.0000x reference)
//
#include <hip/hip_runtime.h>
#include <stdint.h>

// ---------------------------------------------------------------------------
// 3-layer bidirectional LSTM encoder (B=32, T=512, U=256, EMB=300).
// Scan: per direction, 4 WGs x 512 thr, unit-partitioned (64 h-units per WG).
// Fence-free cross-WG protocol: h published as packed dwords via RELAXED
// agent-scope atomic stores (sc1 -> IC, no L2 cache maintenance); readers
// poll the data words directly until nonzero (encoding XOR 0x80008000 with
// -0 clamp guarantees nonzero; slots pre-zeroed). Own quarter of h bypasses
// the IC entirely (LDS). 2 syncthreads/step.
// ---------------------------------------------------------------------------

typedef unsigned short u16;
typedef __bf16 bf16x8 __attribute__((ext_vector_type(8)));
typedef float f32x4 __attribute__((ext_vector_type(4)));

#define SCOPE_AGENT __HIP_MEMORY_SCOPE_AGENT

__device__ __forceinline__ float bf2f(u16 u) { return __uint_as_float(((unsigned)u) << 16); }
__device__ __forceinline__ u16 f2bf(float f) {
  unsigned u = __float_as_uint(f);
  unsigned r = (u + 0x7FFFu + ((u >> 16) & 1u)) >> 16;
  return (u16)r;
}
__device__ __forceinline__ float rdW(const void* p, size_t i, int isf) {
  return isf ? ((const float*)p)[i] : bf2f(((const u16*)p)[i]);
}
__device__ __forceinline__ float sigf(float x) { return 1.f / (1.f + __expf(-x)); }
__device__ __forceinline__ float tanh_(float x) { float e = __expf(2.f * x); return 1.f - 2.f / (e + 1.f); }

// ---- ws layout (bytes) ----
#define O_X0   0ull            // u16 [16384][320]; reused as A23 u16[16384][256]
#define O_WC1  10485760ull     // u16 [2048][320]  (Wi1 B^T, K padded)
#define O_WC2  11796480ull     // u16 [2048][256]
#define O_WC3  12845056ull     // u16 [2048][256]
#define O_WH   13893632ull     // u16 [6][256][1024] canonical bf16 Wh
#define O_BIAS 17039360ull     // float [3][2048]
#define O_FLAG 17063936ull     // uint: 1 = float32 tensors, 0 = bf16
#define O_C0   17076352ull     // float [2][32][256] zeros
#define O_CA   17141888ull
#define O_CB   17207424ull
#define O_CC   17272960ull
#define O_HSA  17338496ull     // u16 [2][513][32][256] (encoded)
#define O_HSB  34148480ull     // u16 [2][513][32][256] (encoded)
#define O_XG   50958464ull     // u16 [16384][2048]

#define HS_U4  1050624         // uint4 count of one hs buffer

// ---------------------------------------------------------------------------
__global__ void k_detect(const unsigned* __restrict__ embw, unsigned* flag) {
  int tid = threadIdx.x;
  unsigned w = embw[tid];
  unsigned e = (w >> 7) & 0xFFu;
  unsigned long long m = __ballot(e >= 100u && e < 128u);
  if (tid == 0) flag[0] = (__popcll(m) >= 32) ? 0u : 1u;
}

// ---------------------------------------------------------------------------
__global__ __launch_bounds__(256) void k_zero(uint4* __restrict__ p, int n) {
  uint4 z = {0u, 0u, 0u, 0u};
  for (int i = blockIdx.x * 256 + threadIdx.x; i < n; i += gridDim.x * 256) p[i] = z;
}

// ---------------------------------------------------------------------------
__global__ __launch_bounds__(256) void k_prep(
    const void* Wi1f, const void* Wi1b, const void* Wi2f, const void* Wi2b,
    const void* Wi3f, const void* Wi3b,
    const void* Wh1f, const void* Wh1b, const void* Wh2f, const void* Wh2b,
    const void* Wh3f, const void* Wh3b,
    const void* b1f, const void* b1b, const void* b2f, const void* b2b,
    const void* b3f, const void* b3b,
    const unsigned* __restrict__ flag,
    u16* Wc1, u16* Wc2, u16* Wc3, u16* WhC, float* bias, float* c0) {
  const int isf = (int)flag[0];
  int idx = blockIdx.x * 256 + threadIdx.x;
  if (idx < 2048 * 320) {  // Wc1[n][k] (B^T), zero-pad k>=300
    int n = idx / 320, k = idx - n * 320;
    int dd = n >> 10, col = n & 1023;
    const void* W = dd ? Wi1b : Wi1f;
    Wc1[idx] = (k < 300) ? f2bf(rdW(W, (size_t)k * 1024 + col, isf)) : (u16)0;
  }
  if (idx < 2048 * 256) {
    int n = idx >> 8, k = idx & 255;
    int dd = n >> 10, col = n & 1023;
    Wc2[idx] = f2bf(rdW(dd ? Wi2b : Wi2f, (size_t)k * 1024 + col, isf));
    Wc3[idx] = f2bf(rdW(dd ? Wi3b : Wi3f, (size_t)k * 1024 + col, isf));
  }
  if (idx < 3 * 2048) {
    int l = idx >> 11, n = idx & 2047;
    int dd = n >> 10, col = n & 1023;
    const void* bp = (l == 0) ? (dd ? b1b : b1f) : (l == 1) ? (dd ? b2b : b2f) : (dd ? b3b : b3f);
    bias[idx] = rdW(bp, col, isf);
  }
  if (idx < 2 * 32 * 256) c0[idx] = 0.f;
  if (idx < 6 * 262144) {  // canonical bf16 Wh copies
    int mat = idx >> 18, pos = idx & 262143;
    const void* W = (mat == 0) ? Wh1f : (mat == 1) ? Wh1b : (mat == 2) ? Wh2f
                   : (mat == 3) ? Wh2b : (mat == 4) ? Wh3f : Wh3b;
    WhC[idx] = f2bf(rdW(W, (size_t)pos, isf));
  }
}

// ---------------------------------------------------------------------------
__global__ __launch_bounds__(256) void k_embed(const int* __restrict__ x,
                                               const void* __restrict__ emb,
                                               const unsigned* __restrict__ flag,
                                               u16* __restrict__ X0) {
  const int isf = (int)flag[0];
  int row = blockIdx.x;              // row = t*32 + b
  int t = row >> 5, b = row & 31;
  int tok = x[b * 512 + t];
  int tid = threadIdx.x;
  if (tid < 150) {
    unsigned pk;
    if (isf) {
      float2 v = *(const float2*)((const float*)emb + (size_t)tok * 300 + tid * 2);
      pk = (unsigned)f2bf(v.x) | ((unsigned)f2bf(v.y) << 16);
    } else {
      pk = *(const unsigned*)((const u16*)emb + (size_t)tok * 300 + tid * 2);
    }
    *(unsigned*)(X0 + (size_t)row * 320 + tid * 2) = pk;
  } else if (tid < 160) {
    *(unsigned*)(X0 + (size_t)row * 320 + 300 + (tid - 150) * 2) = 0u;
  }
}

// ---------------------------------------------------------------------------
// XG[m][n] = A[m][:] . Bt[n][:] + bias[n], M=16384, N=2048, K in {256,320}.
__global__ __launch_bounds__(256) void k_gemm(const u16* __restrict__ A,
                                              const u16* __restrict__ Bt,
                                              const float* __restrict__ bias,
                                              u16* __restrict__ XG, int K) {
  __shared__ u16 As[128 * 32];
  __shared__ u16 Bs[128 * 32];
  const int tid = threadIdx.x;
  const int wv = tid >> 6, L = tid & 63, quad = L >> 4, l15 = L & 15;
  const int wm = wv & 1, wn = wv >> 1;
  const int bm = blockIdx.x & 127, bn = blockIdx.x >> 7;
  const u16* Ab = A + (size_t)(bm * 128) * K;
  const u16* Bb = Bt + (size_t)(bn * 128) * K;
  f32x4 z = {0.f, 0.f, 0.f, 0.f};
  f32x4 acc[4][4];
#pragma unroll
  for (int a = 0; a < 4; ++a)
#pragma unroll
    for (int b2 = 0; b2 < 4; ++b2) acc[a][b2] = z;
  const int srow = tid >> 2, sk = (tid & 3) * 8;
  for (int k0 = 0; k0 < K; k0 += 32) {
    __syncthreads();
    uint4 a0 = *(const uint4*)(Ab + (size_t)srow * K + k0 + sk);
    uint4 a1 = *(const uint4*)(Ab + (size_t)(srow + 64) * K + k0 + sk);
    uint4 b0 = *(const uint4*)(Bb + (size_t)srow * K + k0 + sk);
    uint4 b1 = *(const uint4*)(Bb + (size_t)(srow + 64) * K + k0 + sk);
    *(uint4*)&As[srow * 32 + sk] = a0;
    *(uint4*)&As[(srow + 64) * 32 + sk] = a1;
    *(uint4*)&Bs[srow * 32 + sk] = b0;
    *(uint4*)&Bs[(srow + 64) * 32 + sk] = b1;
    __syncthreads();
    bf16x8 af[4], bf[4];
#pragma unroll
    for (int t4 = 0; t4 < 4; ++t4) {
      af[t4] = *(const bf16x8*)&As[(wm * 64 + t4 * 16 + l15) * 32 + quad * 8];
      bf[t4] = *(const bf16x8*)&Bs[(wn * 64 + t4 * 16 + l15) * 32 + quad * 8];
    }
#pragma unroll
    for (int mt4 = 0; mt4 < 4; ++mt4)
#pragma unroll
      for (int nt4 = 0; nt4 < 4; ++nt4)
        acc[mt4][nt4] = __builtin_amdgcn_mfma_f32_16x16x32_bf16(af[mt4], bf[nt4], acc[mt4][nt4], 0, 0, 0);
  }
#pragma unroll
  for (int mt4 = 0; mt4 < 4; ++mt4)
#pragma unroll
    for (int nt4 = 0; nt4 < 4; ++nt4)
#pragma unroll
      for (int i = 0; i < 4; ++i) {
        int m = bm * 128 + wm * 64 + mt4 * 16 + quad * 4 + i;
        int n = bn * 128 + wn * 64 + nt4 * 16 + l15;
        XG[(size_t)m * 2048 + n] = f2bf(acc[mt4][nt4][i] + bias[n]);
      }
}

// ---------------------------------------------------------------------------
// Recurrent scan: 8 WGs x 512 thr. d = wg>>2 direction, q = wg&3 owns local
// units q*64..q*64+63. hs holds ENCODED bf16 pairs (XOR 0x80008000, nonzero).
__global__ __launch_bounds__(512, 2) void k_scan(const u16* __restrict__ XG,
                                                 const u16* __restrict__ Whf,
                                                 const u16* __restrict__ Whb,
                                                 u16* hs, const u16* h0src,
                                                 const float* __restrict__ c_src,
                                                 float* __restrict__ c_dst) {
  const int wg = blockIdx.x;
  const int d = wg >> 2, q = wg & 3;
  const int tid = threadIdx.x;
  const int wv = tid >> 6, L = tid & 63, quad = L >> 4, l15 = L & 15;
  const int mt = wv & 1, ng = wv >> 1;   // ng 0..3 -> n-tiles ng*4 .. ng*4+3

  __shared__ u16 Ah[32][264];      // decoded h_s, full 256 units
  __shared__ float gbuf[32][257];  // gate preacts, local cols 0..255

  const u16* Wh = d ? Whb : Whf;

  // --- preload B fragments: tile nt -> local col ci = nt*16+l15,
  //     global gate col = (ci>>6)*256 + q*64 + (ci&63) ---
  union U8 { u16 s[8]; bf16x8 v; };
  U8 bfrag[4][8];
#pragma unroll
  for (int t = 0; t < 4; ++t) {
    int ci = (ng * 4 + t) * 16 + l15;
    int col = (ci >> 6) * 256 + q * 64 + (ci & 63);
#pragma unroll
    for (int kt = 0; kt < 8; ++kt)
#pragma unroll
      for (int j = 0; j < 8; ++j)
        bfrag[t][kt].s[j] = Wh[(size_t)(kt * 32 + quad * 8 + j) * 1024 + col];
  }

  // --- cell state: thread (b_c, j) owns local units 4j..4j+3 ---
  const int b_c = tid >> 4, j = tid & 15;
  float cv[4];
#pragma unroll
  for (int e = 0; e < 4; ++e)
    cv[e] = c_src[(d * 32 + b_c) * 256 + q * 64 + 4 * j + e];

  unsigned* hw = (unsigned*)hs;

  // --- stage h0 (full 256 units) into Ah, decoded ---
  {
    int hb = tid >> 4, pair0 = (tid & 15) * 8;  // 8 dword pairs per thread
    if (h0src) {
      const unsigned* h0w = (const unsigned*)h0src + ((size_t)(d * 513 + 512) * 32 + hb) * 128 + pair0;
#pragma unroll
      for (int k = 0; k < 8; ++k)
        *(unsigned*)&Ah[hb][(pair0 + k) * 2] = h0w[k] ^ 0x80008000u;
    } else {
#pragma unroll
      for (int k = 0; k < 8; ++k)
        *(unsigned*)&Ah[hb][(pair0 + k) * 2] = 0u;
    }
  }

  // --- XG prefetch for step 0: rows mt*16+quad*4+i, cols d*1024 + gate col ---
  u16 xgr[4][4];
  {
    int tin = d ? 0 : 511;
#pragma unroll
    for (int t = 0; t < 4; ++t) {
      int ci = (ng * 4 + t) * 16 + l15;
      int col = d * 1024 + (ci >> 6) * 256 + q * 64 + (ci & 63);
      const u16* xp = XG + (size_t)(tin * 32 + mt * 16 + quad * 4) * 2048 + col;
#pragma unroll
      for (int i = 0; i < 4; ++i) xgr[t][i] = xp[(size_t)i * 2048];
    }
  }

  for (int s = 0; s < 512; ++s) {
    __syncthreads();  // Ah staged by all threads

    // matvec: g = h_s @ Wh_slice
    f32x4 acc[4] = {{0.f, 0.f, 0.f, 0.f}, {0.f, 0.f, 0.f, 0.f},
                    {0.f, 0.f, 0.f, 0.f}, {0.f, 0.f, 0.f, 0.f}};
#pragma unroll
    for (int kt = 0; kt < 8; ++kt) {
      bf16x8 ah = *(const bf16x8*)&Ah[mt * 16 + l15][kt * 32 + quad * 8];
#pragma unroll
      for (int t = 0; t < 4; ++t)
        acc[t] = __builtin_amdgcn_mfma_f32_16x16x32_bf16(ah, bfrag[t][kt].v, acc[t], 0, 0, 0);
    }

    // gate pre-activations -> gbuf[bb][ci]
#pragma unroll
    for (int t = 0; t < 4; ++t) {
      int ci = (ng * 4 + t) * 16 + l15;
#pragma unroll
      for (int i = 0; i < 4; ++i)
        gbuf[mt * 16 + quad * 4 + i][ci] = acc[t][i] + bf2f(xgr[t][i]);
    }
    __syncthreads();  // gbuf complete; all MFMA reads of Ah done

    // gates (Keras i,f,c,o) for local units 4j..4j+3; publish immediately
    {
      u16 eh[4];
#pragma unroll
      for (int e = 0; e < 4; ++e) {
        int lu = 4 * j + e;
        float gi = gbuf[b_c][lu];
        float gf = gbuf[b_c][64 + lu];
        float gg = gbuf[b_c][128 + lu];
        float go = gbuf[b_c][192 + lu];
        cv[e] = sigf(gf) * cv[e] + sigf(gi) * tanh_(gg);
        float h = sigf(go) * tanh_(cv[e]);
        u16 ev = f2bf(h); if (ev == 0x8000u) ev = 0;
        eh[e] = ev;
      }
      unsigned pk0 = ((unsigned)eh[0] | ((unsigned)eh[1] << 16)) ^ 0x80008000u;
      unsigned pk1 = ((unsigned)eh[2] | ((unsigned)eh[3] << 16)) ^ 0x80008000u;
      size_t base = ((size_t)(d * 513 + s + 1) * 32 + b_c) * 128 + q * 32 + 2 * j;
      __hip_atomic_store(&hw[base],     pk0, __ATOMIC_RELAXED, SCOPE_AGENT);
      __hip_atomic_store(&hw[base + 1], pk1, __ATOMIC_RELAXED, SCOPE_AGENT);
      // own quarter -> LDS directly (no IC round trip)
      *(unsigned*)&Ah[b_c][q * 64 + 4 * j]     = pk0 ^ 0x80008000u;
      *(unsigned*)&Ah[b_c][q * 64 + 4 * j + 2] = pk1 ^ 0x80008000u;
      if (s == 511) {
#pragma unroll
        for (int e = 0; e < 4; ++e)
          c_dst[(d * 32 + b_c) * 256 + q * 64 + 4 * j + e] = cv[e];
      }
    }

    if (s < 511) {
      // prefetch XG for step s+1 (independent of h_{s+1})
      {
        int tin = d ? (s + 1) : (510 - s);
#pragma unroll
        for (int t = 0; t < 4; ++t) {
          int ci = (ng * 4 + t) * 16 + l15;
          int col = d * 1024 + (ci >> 6) * 256 + q * 64 + (ci & 63);
          const u16* xp = XG + (size_t)(tin * 32 + mt * 16 + quad * 4) * 2048 + col;
#pragma unroll
          for (int i = 0; i < 4; ++i) xgr[t][i] = xp[(size_t)i * 2048];
        }
      }

      // poll 3 peer quarters: dwords (b_c, q2*32 + 2j, +1)
      size_t sb = (size_t)(d * 513 + s + 2) * 32;  // note: slab s+1 (next h)
      sb = ((size_t)(d * 513 + s + 1) * 32 + b_c) * 128;
      unsigned v[6];
      size_t pidx[6];
#pragma unroll
      for (int pp = 0; pp < 3; ++pp) {
        int q2 = (q + 1 + pp) & 3;
        pidx[pp * 2]     = sb + q2 * 32 + 2 * j;
        pidx[pp * 2 + 1] = sb + q2 * 32 + 2 * j + 1;
      }
#pragma unroll
      for (int p2 = 0; p2 < 6; ++p2)
        v[p2] = __hip_atomic_load(&hw[pidx[p2]], __ATOMIC_RELAXED, SCOPE_AGENT);
      for (;;) {
        bool all = true;
#pragma unroll
        for (int p2 = 0; p2 < 6; ++p2) {
          if (v[p2] == 0u) {
            all = false;
            v[p2] = __hip_atomic_load(&hw[pidx[p2]], __ATOMIC_RELAXED, SCOPE_AGENT);
          }
        }
        if (all) break;
      }
#pragma unroll
      for (int pp = 0; pp < 3; ++pp) {
        int q2 = (q + 1 + pp) & 3;
        *(unsigned*)&Ah[b_c][q2 * 64 + 4 * j]     = v[pp * 2]     ^ 0x80008000u;
        *(unsigned*)&Ah[b_c][q2 * 64 + 4 * j + 2] = v[pp * 2 + 1] ^ 0x80008000u;
      }
    }
  }
}

// ---------------------------------------------------------------------------
// Next-layer GEMM input: A[t*32+b][u] = bf16( h_f[t+1] + h_b[512-t] ), decode.
__global__ __launch_bounds__(256) void k_mkA(const u16* __restrict__ hs, u16* __restrict__ A23) {
  int row = blockIdx.x;
  int t = row >> 5, b = row & 31, u = threadIdx.x;
  float vf = bf2f(hs[(size_t)(t + 1) * 8192 + b * 256 + u] ^ 0x8000u);
  float vb = bf2f(hs[(size_t)(513 + 512 - t) * 8192 + b * 256 + u] ^ 0x8000u);
  A23[(size_t)row * 256 + u] = f2bf(vf + vb);
}

// ---------------------------------------------------------------------------
__global__ __launch_bounds__(256) void k_epi(const u16* __restrict__ hs,
                                             const float* __restrict__ cC,
                                             const unsigned* __restrict__ flag,
                                             void* __restrict__ outv) {
  const int isf = (int)flag[0];
  float* outf = (float*)outv;
  u16* outb = (u16*)outv;
  int u = threadIdx.x;
  if (blockIdx.x < 16384) {  // out[b][s][u], blockIdx = b*512 + s
    int b = blockIdx.x >> 9, s = blockIdx.x & 511;
    float v = bf2f(hs[(size_t)(s + 1) * 8192 + b * 256 + u] ^ 0x8000u) +
              bf2f(hs[(size_t)(513 + 512 - s) * 8192 + b * 256 + u] ^ 0x8000u);
    size_t o = (size_t)blockIdx.x * 256 + u;
    if (isf) outf[o] = v; else outb[o] = f2bf(v);
  } else {  // final states: hf, cf, hb, cb
    int jj = blockIdx.x - 16384;
    const size_t base = 16384ull * 256;
    float vhf = bf2f(hs[(size_t)512 * 8192 + jj * 256 + u] ^ 0x8000u);
    float vcf = cC[jj * 256 + u];
    float vhb = bf2f(hs[(size_t)1025 * 8192 + jj * 256 + u] ^ 0x8000u);
    float vcb = cC[(32 + jj) * 256 + u];
    size_t o0 = base + (size_t)jj * 256 + u;
    if (isf) {
      outf[o0] = vhf; outf[o0 + 8192] = vcf; outf[o0 + 16384] = vhb; outf[o0 + 24576] = vcb;
    } else {
      outb[o0] = f2bf(vhf); outb[o0 + 8192] = f2bf(vcf);
      outb[o0 + 16384] = f2bf(vhb); outb[o0 + 24576] = f2bf(vcb);
    }
  }
}

// ---------------------------------------------------------------------------
extern "C" void kernel_launch(void* const* d_in, const int* in_sizes, int n_in,
                              void* d_out, int out_size, void* d_ws, size_t ws_size,
                              hipStream_t stream) {
  (void)in_sizes; (void)n_in; (void)out_size; (void)ws_size;
  const int* x   = (const int*)d_in[0];
  const void* emb = d_in[1];
  const void* Wi1f = d_in[2];  const void* Wh1f = d_in[3];  const void* b1f = d_in[4];
  const void* Wi1b = d_in[5];  const void* Wh1b = d_in[6];  const void* b1b = d_in[7];
  const void* Wi2f = d_in[8];  const void* Wh2f = d_in[9];  const void* b2f = d_in[10];
  const void* Wi2b = d_in[11]; const void* Wh2b = d_in[12]; const void* b2b = d_in[13];
  const void* Wi3f = d_in[14]; const void* Wh3f = d_in[15]; const void* b3f = d_in[16];
  const void* Wi3b = d_in[17]; const void* Wh3b = d_in[18]; const void* b3b = d_in[19];

  char* ws = (char*)d_ws;
  u16* X0   = (u16*)(ws + O_X0);
  u16* A23  = (u16*)(ws + O_X0);   // reuse: X0 dead after layer-1 GEMM
  u16* Wc1  = (u16*)(ws + O_WC1);
  u16* Wc2  = (u16*)(ws + O_WC2);
  u16* Wc3  = (u16*)(ws + O_WC3);
  u16* WhC  = (u16*)(ws + O_WH);
  float* bias = (float*)(ws + O_BIAS);
  unsigned* flag = (unsigned*)(ws + O_FLAG);
  float* c0 = (float*)(ws + O_C0);
  float* cA = (float*)(ws + O_CA);
  float* cB = (float*)(ws + O_CB);
  float* cC = (float*)(ws + O_CC);
  u16* hsA = (u16*)(ws + O_HSA);
  u16* hsB = (u16*)(ws + O_HSB);
  u16* XG  = (u16*)(ws + O_XG);

  k_detect<<<1, 64, 0, stream>>>((const unsigned*)emb, flag);
  k_prep<<<6144, 256, 0, stream>>>(Wi1f, Wi1b, Wi2f, Wi2b, Wi3f, Wi3b,
                                   Wh1f, Wh1b, Wh2f, Wh2b, Wh3f, Wh3b,
                                   b1f, b1b, b2f, b2b, b3f, b3b,
                                   flag, Wc1, Wc2, Wc3, WhC, bias, c0);
  k_zero<<<2048, 256, 0, stream>>>((uint4*)hsA, HS_U4);
  k_zero<<<2048, 256, 0, stream>>>((uint4*)hsB, HS_U4);
  k_embed<<<16384, 256, 0, stream>>>(x, emb, flag, X0);

  // layer 1
  k_gemm<<<2048, 256, 0, stream>>>(X0, Wc1, bias + 0, XG, 320);
  k_scan<<<8, 512, 0, stream>>>(XG, WhC + 0 * 262144, WhC + 1 * 262144, hsA, nullptr, c0, cA);
  // layer 2
  k_mkA<<<16384, 256, 0, stream>>>(hsA, A23);
  k_gemm<<<2048, 256, 0, stream>>>(A23, Wc2, bias + 2048, XG, 256);
  k_scan<<<8, 512, 0, stream>>>(XG, WhC + 2 * 262144, WhC + 3 * 262144, hsB, hsA, cA, cB);
  // hsA dead after layer-2 scan consumed h0; re-zero for layer 3
  k_zero<<<2048, 256, 0, stream>>>((uint4*)hsA, HS_U4);
  // layer 3
  k_mkA<<<16384, 256, 0, stream>>>(hsB, A23);
  k_gemm<<<2048, 256, 0, stream>>>(A23, Wc3, bias + 4096, XG, 256);
  k_scan<<<8, 512, 0, stream>>>(XG, WhC + 4 * 262144, WhC + 5 * 262144, hsA, hsB, cB, cC);

  k_epi<<<16416, 256, 0, stream>>>(hsA, cC, flag, d_out);
}

// Round 6
// 4506.694 us; speedup vs baseline: 1.0950x; 1.0950x over previous
//
#include <hip/hip_runtime.h>
#include <stdint.h>

// ---------------------------------------------------------------------------
// 3-layer bidirectional LSTM encoder (B=32, T=512, U=256, EMB=300).
// Scan: 8 WGs/direction x 256 thr, 32 units per WG. N-tiles are assigned so
// each wave owns all FOUR gates of its 16 units -> gate preacts stay in-lane
// (no LDS gate exchange), ONE barrier/step with double-buffered Ah.
// Cross-WG protocol (unchanged from R4/R5): relaxed agent-scope atomics
// (sc1 -> MALL), data-is-the-flag nonzero encoding (XOR 0x8000, -0 clamped),
// slots pre-zeroed. hs layout [d][513][unit 256][batch 32] so publish and
// poll are single u64 per lane. XG laid out [t][d][gate][unit][batch] so the
// per-step xg prefetch is 4 u64 loads.
// ---------------------------------------------------------------------------

typedef unsigned short u16;
typedef unsigned long long u64;
typedef __bf16 bf16x8 __attribute__((ext_vector_type(8)));
typedef float f32x4 __attribute__((ext_vector_type(4)));

#define SCOPE_AGENT __HIP_MEMORY_SCOPE_AGENT

__device__ __forceinline__ float bf2f(u16 u) { return __uint_as_float(((unsigned)u) << 16); }
__device__ __forceinline__ u16 f2bf(float f) {
  unsigned u = __float_as_uint(f);
  unsigned r = (u + 0x7FFFu + ((u >> 16) & 1u)) >> 16;
  return (u16)r;
}
__device__ __forceinline__ float rdW(const void* p, size_t i, int isf) {
  return isf ? ((const float*)p)[i] : bf2f(((const u16*)p)[i]);
}
__device__ __forceinline__ float sigf(float x) { return 1.f / (1.f + __expf(-x)); }
__device__ __forceinline__ float tanh_(float x) { float e = __expf(2.f * x); return 1.f - 2.f / (e + 1.f); }

// ---- ws layout (bytes) ----
#define O_X0   0ull            // u16 [16384][320]; reused as A23 u16[16384][256]
#define O_WC1  10485760ull     // u16 [2048][320]  (Wi1 B^T, K padded)
#define O_WC2  11796480ull     // u16 [2048][256]
#define O_WC3  12845056ull     // u16 [2048][256]
#define O_WH   13893632ull     // u16 [6][256][1024] canonical bf16 Wh
#define O_BIAS 17039360ull     // float [3][2048]
#define O_FLAG 17063936ull     // uint: 1 = float32 tensors, 0 = bf16
#define O_C0   17076352ull     // float [2][32][256] zeros
#define O_CA   17141888ull
#define O_CB   17207424ull
#define O_CC   17272960ull
#define O_HSA  17338496ull     // u16 [2][513][256][32] (encoded)
#define O_HSB  34148480ull     // u16 [2][513][256][32] (encoded)
#define O_XG   50958464ull     // u16 [512][2][4][256][32]  (XGT)

#define HS_U4  1050624         // uint4 count of one hs buffer

// ---------------------------------------------------------------------------
__global__ void k_detect(const unsigned* __restrict__ embw, unsigned* flag) {
  int tid = threadIdx.x;
  unsigned w = embw[tid];
  unsigned e = (w >> 7) & 0xFFu;
  unsigned long long m = __ballot(e >= 100u && e < 128u);
  if (tid == 0) flag[0] = (__popcll(m) >= 32) ? 0u : 1u;
}

// ---------------------------------------------------------------------------
__global__ __launch_bounds__(256) void k_zero(uint4* __restrict__ p, int n) {
  uint4 z = {0u, 0u, 0u, 0u};
  for (int i = blockIdx.x * 256 + threadIdx.x; i < n; i += gridDim.x * 256) p[i] = z;
}

// ---------------------------------------------------------------------------
__global__ __launch_bounds__(256) void k_prep(
    const void* Wi1f, const void* Wi1b, const void* Wi2f, const void* Wi2b,
    const void* Wi3f, const void* Wi3b,
    const void* Wh1f, const void* Wh1b, const void* Wh2f, const void* Wh2b,
    const void* Wh3f, const void* Wh3b,
    const void* b1f, const void* b1b, const void* b2f, const void* b2b,
    const void* b3f, const void* b3b,
    const unsigned* __restrict__ flag,
    u16* Wc1, u16* Wc2, u16* Wc3, u16* WhC, float* bias, float* c0) {
  const int isf = (int)flag[0];
  int idx = blockIdx.x * 256 + threadIdx.x;
  if (idx < 2048 * 320) {  // Wc1[n][k] (B^T), zero-pad k>=300
    int n = idx / 320, k = idx - n * 320;
    int dd = n >> 10, col = n & 1023;
    const void* W = dd ? Wi1b : Wi1f;
    Wc1[idx] = (k < 300) ? f2bf(rdW(W, (size_t)k * 1024 + col, isf)) : (u16)0;
  }
  if (idx < 2048 * 256) {
    int n = idx >> 8, k = idx & 255;
    int dd = n >> 10, col = n & 1023;
    Wc2[idx] = f2bf(rdW(dd ? Wi2b : Wi2f, (size_t)k * 1024 + col, isf));
    Wc3[idx] = f2bf(rdW(dd ? Wi3b : Wi3f, (size_t)k * 1024 + col, isf));
  }
  if (idx < 3 * 2048) {
    int l = idx >> 11, n = idx & 2047;
    int dd = n >> 10, col = n & 1023;
    const void* bp = (l == 0) ? (dd ? b1b : b1f) : (l == 1) ? (dd ? b2b : b2f) : (dd ? b3b : b3f);
    bias[idx] = rdW(bp, col, isf);
  }
  if (idx < 2 * 32 * 256) c0[idx] = 0.f;
  if (idx < 6 * 262144) {  // canonical bf16 Wh copies
    int mat = idx >> 18, pos = idx & 262143;
    const void* W = (mat == 0) ? Wh1f : (mat == 1) ? Wh1b : (mat == 2) ? Wh2f
                   : (mat == 3) ? Wh2b : (mat == 4) ? Wh3f : Wh3b;
    WhC[idx] = f2bf(rdW(W, (size_t)pos, isf));
  }
}

// ---------------------------------------------------------------------------
__global__ __launch_bounds__(256) void k_embed(const int* __restrict__ x,
                                               const void* __restrict__ emb,
                                               const unsigned* __restrict__ flag,
                                               u16* __restrict__ X0) {
  const int isf = (int)flag[0];
  int row = blockIdx.x;              // row = t*32 + b
  int t = row >> 5, b = row & 31;
  int tok = x[b * 512 + t];
  int tid = threadIdx.x;
  if (tid < 150) {
    unsigned pk;
    if (isf) {
      float2 v = *(const float2*)((const float*)emb + (size_t)tok * 300 + tid * 2);
      pk = (unsigned)f2bf(v.x) | ((unsigned)f2bf(v.y) << 16);
    } else {
      pk = *(const unsigned*)((const u16*)emb + (size_t)tok * 300 + tid * 2);
    }
    *(unsigned*)(X0 + (size_t)row * 320 + tid * 2) = pk;
  } else if (tid < 160) {
    *(unsigned*)(X0 + (size_t)row * 320 + 300 + (tid - 150) * 2) = 0u;
  }
}

// ---------------------------------------------------------------------------
// C[m][n] = A[m][:].Bt[n][:] + bias[n]; written to XGT[t][d][g][u][b].
__global__ __launch_bounds__(256) void k_gemm(const u16* __restrict__ A,
                                              const u16* __restrict__ Bt,
                                              const float* __restrict__ bias,
                                              u16* __restrict__ XGT, int K) {
  __shared__ u16 As[128 * 32];
  __shared__ u16 Bs[128 * 32];
  const int tid = threadIdx.x;
  const int wv = tid >> 6, L = tid & 63, quad = L >> 4, l15 = L & 15;
  const int wm = wv & 1, wn = wv >> 1;
  const int bm = blockIdx.x & 127, bn = blockIdx.x >> 7;
  const u16* Ab = A + (size_t)(bm * 128) * K;
  const u16* Bb = Bt + (size_t)(bn * 128) * K;
  f32x4 z = {0.f, 0.f, 0.f, 0.f};
  f32x4 acc[4][4];
#pragma unroll
  for (int a = 0; a < 4; ++a)
#pragma unroll
    for (int b2 = 0; b2 < 4; ++b2) acc[a][b2] = z;
  const int srow = tid >> 2, sk = (tid & 3) * 8;
  for (int k0 = 0; k0 < K; k0 += 32) {
    __syncthreads();
    uint4 a0 = *(const uint4*)(Ab + (size_t)srow * K + k0 + sk);
    uint4 a1 = *(const uint4*)(Ab + (size_t)(srow + 64) * K + k0 + sk);
    uint4 b0 = *(const uint4*)(Bb + (size_t)srow * K + k0 + sk);
    uint4 b1 = *(const uint4*)(Bb + (size_t)(srow + 64) * K + k0 + sk);
    *(uint4*)&As[srow * 32 + sk] = a0;
    *(uint4*)&As[(srow + 64) * 32 + sk] = a1;
    *(uint4*)&Bs[srow * 32 + sk] = b0;
    *(uint4*)&Bs[(srow + 64) * 32 + sk] = b1;
    __syncthreads();
    bf16x8 af[4], bf[4];
#pragma unroll
    for (int t4 = 0; t4 < 4; ++t4) {
      af[t4] = *(const bf16x8*)&As[(wm * 64 + t4 * 16 + l15) * 32 + quad * 8];
      bf[t4] = *(const bf16x8*)&Bs[(wn * 64 + t4 * 16 + l15) * 32 + quad * 8];
    }
#pragma unroll
    for (int mt4 = 0; mt4 < 4; ++mt4)
#pragma unroll
      for (int nt4 = 0; nt4 < 4; ++nt4)
        acc[mt4][nt4] = __builtin_amdgcn_mfma_f32_16x16x32_bf16(af[mt4], bf[nt4], acc[mt4][nt4], 0, 0, 0);
  }
#pragma unroll
  for (int mt4 = 0; mt4 < 4; ++mt4)
#pragma unroll
    for (int nt4 = 0; nt4 < 4; ++nt4)
#pragma unroll
      for (int i = 0; i < 4; ++i) {
        int m = bm * 128 + wm * 64 + mt4 * 16 + quad * 4 + i;
        int n = bn * 128 + wn * 64 + nt4 * 16 + l15;
        int t = m >> 5, b = m & 31;
        int d = n >> 10, g = (n >> 8) & 3, u = n & 255;
        XGT[(((((size_t)t * 2 + d) * 4 + g) * 256 + u) << 5) + b] =
            f2bf(acc[mt4][nt4][i] + bias[n]);
      }
}

// ---------------------------------------------------------------------------
// Recurrent scan: 16 WGs x 256 thr. d = wg>>3, q = wg&7 (units q*32..q*32+31).
// Waves (mt, hh): m-tile mt, unit-half hh; each wave owns all 4 gates of its
// 16 units. hs is ENCODED [d][513][u][b].
__global__ __launch_bounds__(256, 2) void k_scan(const u16* __restrict__ XGT,
                                                 const u16* __restrict__ Whf,
                                                 const u16* __restrict__ Whb,
                                                 u16* hs, const u16* h0src,
                                                 const float* __restrict__ c_src,
                                                 float* __restrict__ c_dst) {
  const int wg = blockIdx.x;
  const int d = wg >> 3, q = wg & 7;
  const int tid = threadIdx.x;
  const int wv = tid >> 6, L = tid & 63, quad = L >> 4, l15 = L & 15;
  const int mt = wv & 1, hh = wv >> 1;
  const int gu = q * 32 + hh * 16 + l15;   // this lane's unit (B-frag col)

  __shared__ u16 Ah[2][32][264];   // double-buffered decoded h [b][u]

  const u16* Wh = d ? Whb : Whf;

  // --- preload B fragments: gate g cols g*256+gu, k = kt*32 + quad*8 + j ---
  union U8 { u16 s[8]; bf16x8 v; };
  U8 bfrag[4][8];
#pragma unroll
  for (int g = 0; g < 4; ++g)
#pragma unroll
    for (int kt = 0; kt < 8; ++kt)
#pragma unroll
      for (int j = 0; j < 8; ++j)
        bfrag[g][kt].s[j] = Wh[(size_t)(kt * 32 + quad * 8 + j) * 1024 + g * 256 + gu];

  // --- cell state: lane owns (batches mt*16+quad*4+0..3, unit gu) ---
  float cv[4];
#pragma unroll
  for (int i = 0; i < 4; ++i)
    cv[i] = c_src[(d * 32 + mt * 16 + quad * 4 + i) * 256 + gu];

  u64* h64 = (u64*)hs;

  // --- poll offsets (u64 idx within a step slab), 7 peers per thread ---
  int po[7];
#pragma unroll
  for (int k = 0; k < 7; ++k) {
    int flat = tid * 7 + k;
    int pu = flat >> 3, bg = flat & 7;
    int u = pu + (pu >= q * 32 ? 32 : 0);
    po[k] = u * 8 + bg;
  }

  // --- stage h0 into Ah[0]: thread covers unit tid, all 8 batch-groups ---
  if (h0src) {
    const u64* s64 = (const u64*)h0src + (size_t)(d * 513 + 512) * 2048;
#pragma unroll
    for (int r = 0; r < 8; ++r) {
      u64 w = s64[tid * 8 + r];
#pragma unroll
      for (int j = 0; j < 4; ++j)
        Ah[0][r * 4 + j][tid] = (u16)((u16)(w >> (16 * j)) ^ 0x8000u);
    }
  } else {
#pragma unroll
    for (int r = 0; r < 8; ++r)
#pragma unroll
      for (int j = 0; j < 4; ++j) Ah[0][r * 4 + j][tid] = 0;
  }

  // --- xg prefetch for step 0 ---
  const u64* xb = (const u64*)XGT;
  u64 xg[4];
  {
    int tin = d ? 0 : 511;
#pragma unroll
    for (int g = 0; g < 4; ++g)
      xg[g] = xb[((((size_t)tin * 2 + d) * 4 + g) * 256 + gu) * 8 + mt * 4 + quad];
  }

  int p = 0;
  for (int s = 0; s < 512; ++s) {
    __syncthreads();  // Ah[p] complete (staged during step s-1)

    // matvec: all 4 gates for this wave's units
    f32x4 acc[4] = {{0.f, 0.f, 0.f, 0.f}, {0.f, 0.f, 0.f, 0.f},
                    {0.f, 0.f, 0.f, 0.f}, {0.f, 0.f, 0.f, 0.f}};
#pragma unroll
    for (int kt = 0; kt < 8; ++kt) {
      bf16x8 ah = *(const bf16x8*)&Ah[p][mt * 16 + l15][kt * 32 + quad * 8];
#pragma unroll
      for (int g = 0; g < 4; ++g)
        acc[g] = __builtin_amdgcn_mfma_f32_16x16x32_bf16(ah, bfrag[g][kt].v, acc[g], 0, 0, 0);
    }

    // gates (Keras i,f,c,o) in-lane; encode & publish one u64
    u16 eh[4];
#pragma unroll
    for (int i = 0; i < 4; ++i) {
      float gi = acc[0][i] + bf2f((u16)(xg[0] >> (16 * i)));
      float gf = acc[1][i] + bf2f((u16)(xg[1] >> (16 * i)));
      float gc = acc[2][i] + bf2f((u16)(xg[2] >> (16 * i)));
      float go = acc[3][i] + bf2f((u16)(xg[3] >> (16 * i)));
      cv[i] = sigf(gf) * cv[i] + sigf(gi) * tanh_(gc);
      float h = sigf(go) * tanh_(cv[i]);
      u16 e = f2bf(h); if (e == 0x8000u) e = 0;
      eh[i] = (u16)(e ^ 0x8000u);
    }
    u64 pk = (u64)eh[0] | ((u64)eh[1] << 16) | ((u64)eh[2] << 32) | ((u64)eh[3] << 48);
    size_t slab = (size_t)(d * 513 + s + 1) * 2048;
    __hip_atomic_store(&h64[slab + gu * 8 + mt * 4 + quad], pk,
                       __ATOMIC_RELAXED, SCOPE_AGENT);

    const int np = p ^ 1;
    // own units -> Ah[np] directly
#pragma unroll
    for (int i = 0; i < 4; ++i)
      Ah[np][mt * 16 + quad * 4 + i][gu] = (u16)(eh[i] ^ 0x8000u);

    if (s == 511) {
#pragma unroll
      for (int i = 0; i < 4; ++i)
        c_dst[(d * 32 + mt * 16 + quad * 4 + i) * 256 + gu] = cv[i];
    } else {
      // xg prefetch for s+1
      {
        int tin = d ? (s + 1) : (510 - s);
#pragma unroll
        for (int g = 0; g < 4; ++g)
          xg[g] = xb[((((size_t)tin * 2 + d) * 4 + g) * 256 + gu) * 8 + mt * 4 + quad];
      }
      // poll 7 peer u64s (u64 store is atomic: nonzero == published)
      u64 w[7];
#pragma unroll
      for (int k = 0; k < 7; ++k)
        w[k] = __hip_atomic_load(&h64[slab + po[k]], __ATOMIC_RELAXED, SCOPE_AGENT);
      for (;;) {
        bool all = true;
#pragma unroll
        for (int k = 0; k < 7; ++k) {
          if (w[k] == 0ull) {
            all = false;
            w[k] = __hip_atomic_load(&h64[slab + po[k]], __ATOMIC_RELAXED, SCOPE_AGENT);
          }
        }
        if (all) break;
      }
#pragma unroll
      for (int k = 0; k < 7; ++k) {
        int u = po[k] >> 3, bg = po[k] & 7;
#pragma unroll
        for (int j = 0; j < 4; ++j)
          Ah[np][bg * 4 + j][u] = (u16)((u16)(w[k] >> (16 * j)) ^ 0x8000u);
      }
    }
    p = np;
  }
}

// ---------------------------------------------------------------------------
// A23[t*32+b][u] = bf16( dec(hsf[t+1][u][b]) + dec(hsb[512-t][u][b]) ).
__global__ __launch_bounds__(256) void k_mkA(const u16* __restrict__ hs, u16* __restrict__ A23) {
  __shared__ u16 S[32][264];
  int t = blockIdx.x, tid = threadIdx.x;
  const u64* f64 = (const u64*)hs + (size_t)(t + 1) * 2048;
  const u64* b64 = (const u64*)hs + (size_t)(513 + 512 - t) * 2048;
#pragma unroll
  for (int bg = 0; bg < 8; ++bg) {
    u64 wf = f64[tid * 8 + bg], wb = b64[tid * 8 + bg];
#pragma unroll
    for (int j = 0; j < 4; ++j) {
      float vf = bf2f((u16)((u16)(wf >> (16 * j)) ^ 0x8000u));
      float vb = bf2f((u16)((u16)(wb >> (16 * j)) ^ 0x8000u));
      S[bg * 4 + j][tid] = f2bf(vf + vb);
    }
  }
  __syncthreads();
  int b = tid >> 3, uc = tid & 7;
  u16* dst = A23 + ((size_t)t * 32 + b) * 256 + uc * 32;
#pragma unroll
  for (int z = 0; z < 4; ++z)
    *(uint4*)(dst + z * 8) = *(const uint4*)&S[b][uc * 32 + z * 8];
}

// ---------------------------------------------------------------------------
// Epilogue: blocks 0..511 write out[b][s][u]; blocks 512..639 final states.
__global__ __launch_bounds__(256) void k_epi(const u16* __restrict__ hs,
                                             const float* __restrict__ cC,
                                             const unsigned* __restrict__ flag,
                                             void* __restrict__ outv) {
  const int isf = (int)flag[0];
  float* outf = (float*)outv;
  u16* outb = (u16*)outv;
  int tid = threadIdx.x;
  if (blockIdx.x < 512) {
    __shared__ float Sf[32][264];
    int s = blockIdx.x;
    const u64* f64 = (const u64*)hs + (size_t)(s + 1) * 2048;
    const u64* b64 = (const u64*)hs + (size_t)(513 + 512 - s) * 2048;
#pragma unroll
    for (int bg = 0; bg < 8; ++bg) {
      u64 wf = f64[tid * 8 + bg], wb = b64[tid * 8 + bg];
#pragma unroll
      for (int j = 0; j < 4; ++j) {
        float vf = bf2f((u16)((u16)(wf >> (16 * j)) ^ 0x8000u));
        float vb = bf2f((u16)((u16)(wb >> (16 * j)) ^ 0x8000u));
        Sf[bg * 4 + j][tid] = vf + vb;
      }
    }
    __syncthreads();
    int b = tid >> 3, uc = tid & 7;
    size_t o = ((size_t)b * 512 + s) * 256 + uc * 32;
    if (isf) {
#pragma unroll
      for (int z = 0; z < 32; ++z) outf[o + z] = Sf[b][uc * 32 + z];
    } else {
#pragma unroll
      for (int z = 0; z < 16; ++z) {
        unsigned pk = (unsigned)f2bf(Sf[b][uc * 32 + 2 * z]) |
                      ((unsigned)f2bf(Sf[b][uc * 32 + 2 * z + 1]) << 16);
        *(unsigned*)(outb + o + 2 * z) = pk;
      }
    }
  } else {
    int idx = blockIdx.x - 512;       // 0..127
    int which = idx >> 5, b = idx & 31;
    int u = tid;
    float v;
    if (which == 0)      v = bf2f((u16)(hs[(size_t)512 * 8192 + u * 32 + b] ^ 0x8000u));
    else if (which == 1) v = cC[b * 256 + u];
    else if (which == 2) v = bf2f((u16)(hs[(size_t)1025 * 8192 + u * 32 + b] ^ 0x8000u));
    else                 v = cC[(32 + b) * 256 + u];
    size_t o = 16384ull * 256 + (size_t)which * 8192 + b * 256 + u;
    if (isf) outf[o] = v; else outb[o] = f2bf(v);
  }
}

// ---------------------------------------------------------------------------
extern "C" void kernel_launch(void* const* d_in, const int* in_sizes, int n_in,
                              void* d_out, int out_size, void* d_ws, size_t ws_size,
                              hipStream_t stream) {
  (void)in_sizes; (void)n_in; (void)out_size; (void)ws_size;
  const int* x   = (const int*)d_in[0];
  const void* emb = d_in[1];
  const void* Wi1f = d_in[2];  const void* Wh1f = d_in[3];  const void* b1f = d_in[4];
  const void* Wi1b = d_in[5];  const void* Wh1b = d_in[6];  const void* b1b = d_in[7];
  const void* Wi2f = d_in[8];  const void* Wh2f = d_in[9];  const void* b2f = d_in[10];
  const void* Wi2b = d_in[11]; const void* Wh2b = d_in[12]; const void* b2b = d_in[13];
  const void* Wi3f = d_in[14]; const void* Wh3f = d_in[15]; const void* b3f = d_in[16];
  const void* Wi3b = d_in[17]; const void* Wh3b = d_in[18]; const void* b3b = d_in[19];

  char* ws = (char*)d_ws;
  u16* X0   = (u16*)(ws + O_X0);
  u16* A23  = (u16*)(ws + O_X0);   // reuse: X0 dead after layer-1 GEMM
  u16* Wc1  = (u16*)(ws + O_WC1);
  u16* Wc2  = (u16*)(ws + O_WC2);
  u16* Wc3  = (u16*)(ws + O_WC3);
  u16* WhC  = (u16*)(ws + O_WH);
  float* bias = (float*)(ws + O_BIAS);
  unsigned* flag = (unsigned*)(ws + O_FLAG);
  float* c0 = (float*)(ws + O_C0);
  float* cA = (float*)(ws + O_CA);
  float* cB = (float*)(ws + O_CB);
  float* cC = (float*)(ws + O_CC);
  u16* hsA = (u16*)(ws + O_HSA);
  u16* hsB = (u16*)(ws + O_HSB);
  u16* XGT = (u16*)(ws + O_XG);

  k_detect<<<1, 64, 0, stream>>>((const unsigned*)emb, flag);
  k_prep<<<6144, 256, 0, stream>>>(Wi1f, Wi1b, Wi2f, Wi2b, Wi3f, Wi3b,
                                   Wh1f, Wh1b, Wh2f, Wh2b, Wh3f, Wh3b,
                                   b1f, b1b, b2f, b2b, b3f, b3b,
                                   flag, Wc1, Wc2, Wc3, WhC, bias, c0);
  k_zero<<<2048, 256, 0, stream>>>((uint4*)hsA, HS_U4);
  k_zero<<<2048, 256, 0, stream>>>((uint4*)hsB, HS_U4);
  k_embed<<<16384, 256, 0, stream>>>(x, emb, flag, X0);

  // layer 1
  k_gemm<<<2048, 256, 0, stream>>>(X0, Wc1, bias + 0, XGT, 320);
  k_scan<<<16, 256, 0, stream>>>(XGT, WhC + 0 * 262144, WhC + 1 * 262144, hsA, nullptr, c0, cA);
  // layer 2
  k_mkA<<<512, 256, 0, stream>>>(hsA, A23);
  k_gemm<<<2048, 256, 0, stream>>>(A23, Wc2, bias + 2048, XGT, 256);
  k_scan<<<16, 256, 0, stream>>>(XGT, WhC + 2 * 262144, WhC + 3 * 262144, hsB, hsA, cA, cB);
  // hsA dead after layer-2 scan consumed h0; re-zero for layer 3
  k_zero<<<2048, 256, 0, stream>>>((uint4*)hsA, HS_U4);
  // layer 3
  k_mkA<<<512, 256, 0, stream>>>(hsB, A23);
  k_gemm<<<2048, 256, 0, stream>>>(A23, Wc3, bias + 4096, XGT, 256);
  k_scan<<<16, 256, 0, stream>>>(XGT, WhC + 4 * 262144, WhC + 5 * 262144, hsA, hsB, cB, cC);

  k_epi<<<640, 256, 0, stream>>>(hsA, cC, flag, d_out);
}